// Round 8
// baseline (485.799 us; speedup 1.0000x reference)
//
#include <hip/hip_runtime.h>
#include <hip/hip_bf16.h>
#include <stdint.h>

// Problem constants
#define NQ    2304          // H*W = 48*48 tokens
#define MROWS 4608          // B*NQ
#define DIMC  768
#define NHEAD 12
#define HEADS 24            // B*NH
#define HD    64

typedef unsigned int uint;
typedef unsigned short u16;
typedef __attribute__((ext_vector_type(8))) short s16x8;   // 8 bf16 = 4 VGPR
typedef __attribute__((ext_vector_type(4))) float f32x4;   // mfma acc

#define MFMA16(a, b, c) __builtin_amdgcn_mfma_f32_16x16x32_bf16((a), (b), (c), 0, 0, 0)

static __device__ __forceinline__ float bfbits2f(uint u) {
  union { uint i; float f; } c; c.i = u << 16; return c.f;
}
static __device__ __forceinline__ u16 f2bf(float f) {
  __hip_bfloat16 h = __float2bfloat16(f);
  union { __hip_bfloat16 h; u16 u; } c; c.h = h; return c.u;
}
static __device__ __forceinline__ u16 f2h(float f) {
  union { _Float16 h; u16 u; } c; c.h = (_Float16)f; return c.u;
}
static __device__ __forceinline__ float h2f(u16 u) {
  union { u16 u; _Float16 h; } c; c.u = u; return (float)c.h;
}
static __device__ __forceinline__ void dec8(uint4 p, float* f) {
  f[0] = bfbits2f(p.x & 0xFFFFu); f[1] = bfbits2f(p.x >> 16);
  f[2] = bfbits2f(p.y & 0xFFFFu); f[3] = bfbits2f(p.y >> 16);
  f[4] = bfbits2f(p.z & 0xFFFFu); f[5] = bfbits2f(p.z >> 16);
  f[6] = bfbits2f(p.w & 0xFFFFu); f[7] = bfbits2f(p.w >> 16);
}
// dual-dtype 8-element load -> fp32 (bf=1: bf16, bf=0: fp32)
static __device__ __forceinline__ void ld8(const void* p, size_t idx, int bf, float* f) {
  if (bf) { dec8(*(const uint4*)((const u16*)p + idx), f); }
  else {
    const float4* q = (const float4*)((const float*)p + idx);
    float4 a = q[0], b = q[1];
    f[0] = a.x; f[1] = a.y; f[2] = a.z; f[3] = a.w;
    f[4] = b.x; f[5] = b.y; f[6] = b.z; f[7] = b.w;
  }
}
static __device__ __forceinline__ float ld1(const void* p, size_t idx, int bf) {
  return bf ? bfbits2f(((const u16*)p)[idx]) : ((const float*)p)[idx];
}
// dual-dtype 8-element load -> packed bf16 (uint4)
static __device__ __forceinline__ uint4 ld8_to_bf(const void* p, size_t idx, int bf) {
  if (bf) return *(const uint4*)((const u16*)p + idx);
  float f[8]; ld8(p, idx, 0, f);
  uint4 u;
  u.x = (uint)f2bf(f[0]) | ((uint)f2bf(f[1]) << 16);
  u.y = (uint)f2bf(f[2]) | ((uint)f2bf(f[3]) << 16);
  u.z = (uint)f2bf(f[4]) | ((uint)f2bf(f[5]) << 16);
  u.w = (uint)f2bf(f[6]) | ((uint)f2bf(f[7]) << 16);
  return u;
}

// ---------------------------------------------------------------------------
// K0: dtype detector (unchanged — PASSED; do not touch).
// ---------------------------------------------------------------------------
__global__ __launch_bounds__(64) void detect_k(const u16* __restrict__ x,
                                               int* __restrict__ mode) {
  int t = threadIdx.x;
  int cnt = 0;
  for (int i = 0; i < 32; ++i) {
    uint u = x[(size_t)(t * 32 + i) * 2];
    uint e = (u >> 7) & 0xFFu;
    uint mag = u & 0x7FFFu;
    if (mag == 0 || (e >= 113 && e <= 133)) cnt++;
  }
#pragma unroll
  for (int d = 1; d < 64; d <<= 1) cnt += __shfl_xor(cnt, d);
  if (t == 0) mode[0] = (cnt > 1024) ? 1 : 0;
}

// ---------------------------------------------------------------------------
// K1: QKV projection, MFMA.  V stored TRANSPOSED: Vt[(bh*HD + d)*NQ + n]
// so attn loads V^T B-frags directly from global. Q/K row-major. (unchanged)
// ---------------------------------------------------------------------------
__global__ __launch_bounds__(256) void qkv_gemm_k(
    const void* __restrict__ Xp, const void* __restrict__ Wp,
    const void* __restrict__ Bq, const int* __restrict__ mode,
    u16* __restrict__ Q, u16* __restrict__ K, u16* __restrict__ Vt)
{
  __shared__ __align__(16) u16 As[128][40];
  __shared__ __align__(16) u16 Bs[128][40];
  const int bf = mode[0];
  const int t = threadIdx.x;
  const int w = t >> 6, l15 = t & 15, quad = (t >> 4) & 3;
  const int wr = w >> 1, wc = w & 1;
  const int row0 = blockIdx.y << 7, col0 = blockIdx.x << 7;
  const int lr = t >> 1, lk = (t & 1) << 4;

  f32x4 zero4 = {0.f, 0.f, 0.f, 0.f};
  f32x4 acc[4][4];
#pragma unroll
  for (int i = 0; i < 4; ++i)
#pragma unroll
    for (int j = 0; j < 4; ++j) acc[i][j] = zero4;

  for (int kt = 0; kt < DIMC; kt += 32) {
    __syncthreads();
    *(uint4*)&As[lr][lk]     = ld8_to_bf(Xp, (size_t)(row0 + lr) * DIMC + kt + lk, bf);
    *(uint4*)&As[lr][lk + 8] = ld8_to_bf(Xp, (size_t)(row0 + lr) * DIMC + kt + lk + 8, bf);
    *(uint4*)&Bs[lr][lk]     = ld8_to_bf(Wp, (size_t)(col0 + lr) * DIMC + kt + lk, bf);
    *(uint4*)&Bs[lr][lk + 8] = ld8_to_bf(Wp, (size_t)(col0 + lr) * DIMC + kt + lk + 8, bf);
    __syncthreads();
    s16x8 af[4], bfr[4];
#pragma unroll
    for (int i = 0; i < 4; ++i)
      af[i] = *(const s16x8*)&As[(wr << 6) + (i << 4) + l15][quad << 3];
#pragma unroll
    for (int j = 0; j < 4; ++j)
      bfr[j] = *(const s16x8*)&Bs[(wc << 6) + (j << 4) + l15][quad << 3];
#pragma unroll
    for (int i = 0; i < 4; ++i)
#pragma unroll
      for (int j = 0; j < 4; ++j)
        acc[i][j] = MFMA16(af[i], bfr[j], acc[i][j]);
  }

#pragma unroll
  for (int jt = 0; jt < 4; ++jt) {
    int col = col0 + (wc << 6) + (jt << 4) + l15;     // 0..2303
    int which = col / DIMC;
    int rem = col - which * DIMC;
    int head = rem >> 6, d = rem & 63;
    float bv = ld1(Bq, col, bf);
#pragma unroll
    for (int i = 0; i < 4; ++i)
#pragma unroll
      for (int r = 0; r < 4; ++r) {
        int mrow = row0 + (wr << 6) + (i << 4) + (quad << 2) + r;
        int b_ = (mrow >= NQ) ? 1 : 0;
        int n = mrow - b_ * NQ;
        u16 val = f2bf(acc[i][jt][r] + bv);
        size_t bh = (size_t)(b_ * NHEAD + head);
        if (which == 2)      Vt[(bh * HD + d) * NQ + n] = val;     // transposed
        else if (which == 1) K[(bh * NQ + n) * HD + d] = val;
        else                 Q[(bh * NQ + n) * HD + d] = val;
      }
  }
}

// ---------------------------------------------------------------------------
// K1b: bias precompute as MFMA GEMM (round 7, verified; unchanged).
// T[n][j] = q[n]·rel[j]; scatter to fp16 tables [bh][c][n].
// ---------------------------------------------------------------------------
__global__ __launch_bounds__(256) void bias_gemm_k(
    const u16* __restrict__ Qw,
    const void* __restrict__ rph, const void* __restrict__ rpw,
    const int* __restrict__ mode,
    u16* __restrict__ Bh_g, u16* __restrict__ Bw_g)
{
  __shared__ __align__(16) u16 As[128][72];
  __shared__ __align__(16) u16 Bs[192][72];
  const int bf = mode[0];
  const int t = threadIdx.x;
  const int w = t >> 6, l15 = t & 15, quad = (t >> 4) & 3;
  const int wr = w >> 1, wc = w & 1;
  const int blk = blockIdx.x;          // 0..431
  const int bhd = blk / 18;
  const int row0 = (blk - bhd * 18) << 7;

  // stage A: 128 q-rows x 64 k (bf16 native, coalesced)
  {
    int lr = t >> 1, lk = (t & 1) << 5;
    const u16* src = Qw + ((size_t)bhd * NQ + row0 + lr) * HD + lk;
    *(uint4*)&As[lr][lk]      = *(const uint4*)(src);
    *(uint4*)&As[lr][lk + 8]  = *(const uint4*)(src + 8);
    *(uint4*)&As[lr][lk + 16] = *(const uint4*)(src + 16);
    *(uint4*)&As[lr][lk + 24] = *(const uint4*)(src + 24);
  }
  // stage B: rows 0..94 = rel_h, 96..190 = rel_w (pad rows clamped)
  for (int e = t; e < 384; e += 256) {
    int row = e >> 1, k32 = (e & 1) << 5;
    int tab = (row >= 96) ? 1 : 0;
    int r2 = row - (tab ? 96 : 0);
    if (r2 > 94) r2 = 0;
    const void* src = tab ? rpw : rph;
    *(uint4*)&Bs[row][k32]      = ld8_to_bf(src, (size_t)r2 * HD + k32, bf);
    *(uint4*)&Bs[row][k32 + 8]  = ld8_to_bf(src, (size_t)r2 * HD + k32 + 8, bf);
    *(uint4*)&Bs[row][k32 + 16] = ld8_to_bf(src, (size_t)r2 * HD + k32 + 16, bf);
    *(uint4*)&Bs[row][k32 + 24] = ld8_to_bf(src, (size_t)r2 * HD + k32 + 24, bf);
  }
  __syncthreads();

  f32x4 zero4 = {0.f, 0.f, 0.f, 0.f};
  f32x4 acc[4][6];
#pragma unroll
  for (int i = 0; i < 4; ++i)
#pragma unroll
    for (int j = 0; j < 6; ++j) acc[i][j] = zero4;

#pragma unroll
  for (int ks = 0; ks < 2; ++ks) {
    s16x8 af[4], bfr[6];
#pragma unroll
    for (int i = 0; i < 4; ++i)
      af[i] = *(const s16x8*)&As[(wr << 6) + (i << 4) + l15][(ks << 5) + (quad << 3)];
#pragma unroll
    for (int j = 0; j < 6; ++j)
      bfr[j] = *(const s16x8*)&Bs[wc * 96 + (j << 4) + l15][(ks << 5) + (quad << 3)];
#pragma unroll
    for (int i = 0; i < 4; ++i)
#pragma unroll
      for (int j = 0; j < 6; ++j)
        acc[i][j] = MFMA16(af[i], bfr[j], acc[i][j]);
  }

  // scatter epilogue: col j of table tab -> c = coord(n)+47-j  (0..47 valid)
#pragma unroll
  for (int jt = 0; jt < 6; ++jt) {
    int col = wc * 96 + (jt << 4) + l15;     // 0..191
    int tab = (col >= 96) ? 1 : 0;
    int j = col - (tab ? 96 : 0);
    if (j >= 95) continue;
    u16* dstT = tab ? Bw_g : Bh_g;
#pragma unroll
    for (int i = 0; i < 4; ++i)
#pragma unroll
      for (int r = 0; r < 4; ++r) {
        int n = row0 + (wr << 6) + (i << 4) + (quad << 2) + r;
        int qh = (n * 10923) >> 19;
        int coord = tab ? (n - qh * 48) : qh;
        int c = coord + 47 - j;
        if (c >= 0 && c < 48)
          dstT[((size_t)bhd * 48 + c) * NQ + n] = f2h(acc[i][jt][r]);
      }
  }
}

// ---------------------------------------------------------------------------
// K2: MFMA flash attention, round 8: maximize resident waves.
//  Evidence r6/r7: r6 body = 64 VGPR (8 waves/SIMD class) but LDS 25.6 KB
//  capped 6 blocks/CU (occ 35%); r7 prefetch pushed VGPR to 96 (4-wave
//  class, occ 21%) — occupancy loss ate the ILP gain. Fix: r6 body (64
//  VGPR, no K prefetch) + fp16 bias tables (12.8 KB LDS) -> 8 blocks/CU =
//  32 waves/CU; S=3 supplies 10 blocks/CU of work, nearly all co-resident.
//  fp16 bias precision proven in rounds 0-2 (same absmax).
// ---------------------------------------------------------------------------
__global__ __launch_bounds__(256) void attn_k(
    const u16* __restrict__ Qw, const u16* __restrict__ Kw,
    const u16* __restrict__ Vtg,
    const u16* __restrict__ Bh_g, const u16* __restrict__ Bw_g,
    int S, float* __restrict__ Opart, float* __restrict__ Lpart,
    u16* __restrict__ Aout)
{
  __shared__ __align__(16) u16 BhL[48][64];   // fp16 [kh][local qrow]   6.0 KB
  __shared__ __align__(16) u16 BwL[64][52];   // fp16 [local qrow][kw]   6.5 KB

  // XCD swizzle: nwg = 864*S (div by 8). XCD x runs heads 3x..3x+2 only ->
  // per-XCD K/V working set 1.76 MB -> L2-resident.
  const int bid = blockIdx.x;
  const int xcd = bid & 7;
  const int local = bid >> 3;            // [0, 108*S)
  const int per_head = 36 * S;
  const int head_l = local / per_head;   // 0..2
  const int rem = local - head_l * per_head;
  const int qb = rem / S;
  const int z = rem - qb * S;
  const int bhd = xcd * 3 + head_l;
  const int q0 = qb << 6;
  const int span = NQ / S;               // 2304/1152/768 (mult of 48 & 64)
  const int kt_lo = z * span, kt_hi = kt_lo + span;

  const int t = threadIdx.x;
  const int w = t >> 6, l15 = t & 15, quad = (t >> 4) & 3;
  const float scale = 0.125f;   // 64^-0.5

  const u16* kbase  = Kw  + (size_t)bhd * NQ * HD;
  const u16* vtbase = Vtg + (size_t)bhd * HD * NQ;
  const int q0w = q0 + (w << 4);
  const int qrl = (w << 4) + l15;        // this lane's local q row

  // ---- LDS fill from precomputed fp16 tables (coalesced reads, raw copy)
  for (int e = t; e < 48 * 64; e += 256) {
    int c = e >> 6, r = e & 63;
    size_t gi = ((size_t)bhd * 48 + c) * NQ + q0 + r;
    BhL[c][r] = Bh_g[gi];
    BwL[r][c] = Bw_g[gi];
  }

  // Q B-frags (loop-invariant): B[n=qrow=l15][k=quad*8+j]
  const u16* qfrag = Qw + ((size_t)bhd * NQ + q0w + l15) * HD + (quad << 3);
  s16x8 qa0 = *(const s16x8*)(qfrag);
  s16x8 qa1 = *(const s16x8*)(qfrag + 32);

  __syncthreads();   // bias tables visible

  f32x4 zero4 = {0.f, 0.f, 0.f, 0.f};
  f32x4 acc_o[4];
#pragma unroll
  for (int nc = 0; nc < 4; ++nc) acc_o[nc] = zero4;
  float l_st = 0.f;   // lane-local partial sum of exp(S); reduced in epilogue
  int km = 0;         // kt0 % 48; kt_lo % 48 == 0 for all splits

  for (int kt0 = kt_lo; kt0 < kt_hi; kt0 += 64) {
    // S^T = K Q^T : lane holds S[key = kt0+16*nc+4*quad+r][qrow = qrl]
    f32x4 acc_s[4];
#pragma unroll
    for (int nc = 0; nc < 4; ++nc) {
      const u16* kp = kbase + (size_t)(kt0 + (nc << 4) + l15) * HD + (quad << 3);
      s16x8 kb0 = *(const s16x8*)(kp);
      s16x8 kb1 = *(const s16x8*)(kp + 32);
      f32x4 a = MFMA16(kb0, qa0, zero4);
      acc_s[nc] = MFMA16(kb1, qa1, a);
    }

    // V^T frag loads (half 0) issued now; latency flies under softmax VALU
    s16x8 vb0[4];
#pragma unroll
    for (int nc = 0; nc < 4; ++nc) {
      const u16* vp = vtbase + (size_t)((nc << 4) + l15) * NQ + kt0 + (quad << 3);
      vb0[nc] = *(const s16x8*)(vp);
    }

    // bias reads: Bh 2 fp16 scalars; Bw one ds_read_b64 (4 fp16) per nc-group
    int kh0 = (kt0 * 10923) >> 19;
    float bh0v = h2f(BhL[kh0][qrl]);
    float bh1v = h2f(BhL[kh0 + 1][qrl]);     // kh0 <= 46 always
    int thr = (kh0 + 1) * 48 - kt0;          // local key >= thr -> kh0+1
    float bwf[16];
#pragma unroll
    for (int nc = 0; nc < 4; ++nc) {
      int bnc = km + (nc << 4);
      bnc = (bnc >= 48) ? bnc - 48 : bnc;    // in {0,16,32}; +4*quad+3 <= 47
      uint2 pv = *(const uint2*)&BwL[qrl][bnc + (quad << 2)];
      bwf[(nc << 2) + 0] = h2f((u16)(pv.x & 0xFFFFu));
      bwf[(nc << 2) + 1] = h2f((u16)(pv.x >> 16));
      bwf[(nc << 2) + 2] = h2f((u16)(pv.y & 0xFFFFu));
      bwf[(nc << 2) + 3] = h2f((u16)(pv.y >> 16));
    }

    // scale + bias -> exp (no max subtraction: scores bounded)
    float sv[16];
    float sum = 0.f;
#pragma unroll
    for (int nc = 0; nc < 4; ++nc)
#pragma unroll
      for (int r = 0; r < 4; ++r) {
        int kl = (nc << 4) + (quad << 2) + r;
        float s = acc_s[nc][r] * scale + ((kl >= thr) ? bh1v : bh0v) + bwf[(nc << 2) + r];
        s = __expf(s);
        sv[(nc << 2) + r] = s;
        sum += s;
      }
    l_st += sum;

    // P -> A-frags via cross-quad shfl exchange (two key-halves).
    // A[m=l15(qrow)][k=quad*8+j (key)].
    int srcA = ((quad & 1) << 5) + l15;   // source quad 2*(quad&1)
    int srcB = srcA + 16;                 // source quad 2*(quad&1)+1
    int hi = quad >> 1;
    // half 0: keys kt0+0..31
    {
      uint W0 = (uint)f2bf(sv[0]) | ((uint)f2bf(sv[1]) << 16);
      uint W1 = (uint)f2bf(sv[2]) | ((uint)f2bf(sv[3]) << 16);
      uint W2 = (uint)f2bf(sv[4]) | ((uint)f2bf(sv[5]) << 16);
      uint W3 = (uint)f2bf(sv[6]) | ((uint)f2bf(sv[7]) << 16);
      union { uint u[4]; s16x8 v; } pf;
      uint e0 = __shfl(W0, srcA), e1 = __shfl(W1, srcA), e2 = __shfl(W2, srcA), e3 = __shfl(W3, srcA);
      pf.u[0] = hi ? e2 : e0; pf.u[1] = hi ? e3 : e1;
      uint g0 = __shfl(W0, srcB), g1 = __shfl(W1, srcB), g2 = __shfl(W2, srcB), g3 = __shfl(W3, srcB);
      pf.u[2] = hi ? g2 : g0; pf.u[3] = hi ? g3 : g1;
#pragma unroll
      for (int nc = 0; nc < 4; ++nc)
        acc_o[nc] = MFMA16(pf.v, vb0[nc], acc_o[nc]);
    }
    // half 1: keys kt0+32..63 (V loads issued here, hidden by half-0 MFMAs)
    {
      s16x8 vb1[4];
#pragma unroll
      for (int nc = 0; nc < 4; ++nc) {
        const u16* vp = vtbase + (size_t)((nc << 4) + l15) * NQ + kt0 + 32 + (quad << 3);
        vb1[nc] = *(const s16x8*)(vp);
      }
      uint W4 = (uint)f2bf(sv[8])  | ((uint)f2bf(sv[9])  << 16);
      uint W5 = (uint)f2bf(sv[10]) | ((uint)f2bf(sv[11]) << 16);
      uint W6 = (uint)f2bf(sv[12]) | ((uint)f2bf(sv[13]) << 16);
      uint W7 = (uint)f2bf(sv[14]) | ((uint)f2bf(sv[15]) << 16);
      union { uint u[4]; s16x8 v; } pf;
      uint e0 = __shfl(W4, srcA), e1 = __shfl(W5, srcA), e2 = __shfl(W6, srcA), e3 = __shfl(W7, srcA);
      pf.u[0] = hi ? e2 : e0; pf.u[1] = hi ? e3 : e1;
      uint g0 = __shfl(W4, srcB), g1 = __shfl(W5, srcB), g2 = __shfl(W6, srcB), g3 = __shfl(W7, srcB);
      pf.u[2] = hi ? g2 : g0; pf.u[3] = hi ? g3 : g1;
#pragma unroll
      for (int nc = 0; nc < 4; ++nc)
        acc_o[nc] = MFMA16(pf.v, vb1[nc], acc_o[nc]);
    }
    km += 16;
    if (km >= 48) km -= 48;
  }

  // reduce l across quads (each lane then has full sum for qrow = q0w+l15)
  l_st += __shfl_xor(l_st, 16);
  l_st += __shfl_xor(l_st, 32);

  if (S > 1) {
    // partial path: unnormalized f32 O + l per split
    float* Op = Opart + ((size_t)(z * HEADS + bhd) * NQ + q0) * HD;
#pragma unroll
    for (int r = 0; r < 4; ++r) {
      int row = (w << 4) + (quad << 2) + r;
#pragma unroll
      for (int nc = 0; nc < 4; ++nc)
        Op[(size_t)row * HD + (nc << 4) + l15] = acc_o[nc][r];
    }
    if (quad == 0)
      Lpart[(size_t)(z * HEADS + bhd) * NQ + q0w + l15] = l_st;
  } else {
    // direct path: divide by l (broadcast from lane l15 == 4*quad+r)
    int b_ = bhd / NHEAD, head = bhd - b_ * NHEAD;
    float invl = 1.f / l_st;
    int bsrc = (quad << 4) + (quad << 2);
#pragma unroll
    for (int r = 0; r < 4; ++r) {
      float inv = __shfl(invl, bsrc + r);
      int token = q0 + (w << 4) + (quad << 2) + r;
      u16* dst = Aout + ((size_t)b_ * NQ + token) * DIMC + (head << 6);
#pragma unroll
      for (int nc = 0; nc < 4; ++nc)
        dst[(nc << 4) + l15] = f2bf(acc_o[nc][r] * inv);
    }
  }
}

// ---------------------------------------------------------------------------
// K2b: combine split-K partials: O = (sum_z O_z) / (sum_z l_z), store bf16.
// ---------------------------------------------------------------------------
__global__ __launch_bounds__(256) void combine_k(
    const float* __restrict__ Op, const float* __restrict__ Lp,
    int S, u16* __restrict__ Aout)
{
  int idx = blockIdx.x * 256 + threadIdx.x;   // 0 .. 884735
  int m = idx / 192;                          // row 0..4607 (DIMC/4 = 192)
  int cq = idx - m * 192;
  int ccol = cq << 2;
  int head = ccol >> 6, d0 = ccol & 63;
  int b_ = (m >= NQ) ? 1 : 0;
  int n = m - b_ * NQ;
  int bh = b_ * NHEAD + head;
  float ox = 0.f, oy = 0.f, oz = 0.f, ow = 0.f, ls = 0.f;
  for (int zz = 0; zz < S; ++zz) {
    const float* ob = Op + ((size_t)(zz * HEADS + bh) * NQ + n) * HD + d0;
    float4 v = *(const float4*)ob;
    ox += v.x; oy += v.y; oz += v.z; ow += v.w;
    ls += Lp[(size_t)(zz * HEADS + bh) * NQ + n];
  }
  float inv = 1.f / ls;
  u16* dst = Aout + (size_t)m * DIMC + ccol;
  dst[0] = f2bf(ox * inv); dst[1] = f2bf(oy * inv);
  dst[2] = f2bf(oz * inv); dst[3] = f2bf(ow * inv);
}

// ---------------------------------------------------------------------------
// K3: output projection, MFMA (unchanged).
// ---------------------------------------------------------------------------
__global__ __launch_bounds__(256) void proj_gemm_k(
    const u16* __restrict__ A, const void* __restrict__ Wp,
    const void* __restrict__ Bp, const int* __restrict__ mode,
    void* __restrict__ Out)
{
  __shared__ __align__(16) u16 As[128][40];
  __shared__ __align__(16) u16 Bs[128][40];
  const int bf = mode[0];
  const int t = threadIdx.x;
  const int w = t >> 6, l15 = t & 15, quad = (t >> 4) & 3;
  const int wr = w >> 1, wc = w & 1;
  const int row0 = blockIdx.y << 7, col0 = blockIdx.x << 7;
  const int lr = t >> 1, lk = (t & 1) << 4;

  f32x4 zero4 = {0.f, 0.f, 0.f, 0.f};
  f32x4 acc[4][4];
#pragma unroll
  for (int i = 0; i < 4; ++i)
#pragma unroll
    for (int j = 0; j < 4; ++j) acc[i][j] = zero4;

  for (int kt = 0; kt < DIMC; kt += 32) {
    __syncthreads();
    *(uint4*)&As[lr][lk]     = *(const uint4*)(A + (size_t)(row0 + lr) * DIMC + kt + lk);
    *(uint4*)&As[lr][lk + 8] = *(const uint4*)(A + (size_t)(row0 + lr) * DIMC + kt + lk + 8);
    *(uint4*)&Bs[lr][lk]     = ld8_to_bf(Wp, (size_t)(col0 + lr) * DIMC + kt + lk, bf);
    *(uint4*)&Bs[lr][lk + 8] = ld8_to_bf(Wp, (size_t)(col0 + lr) * DIMC + kt + lk + 8, bf);
    __syncthreads();
    s16x8 af[4], bfr[4];
#pragma unroll
    for (int i = 0; i < 4; ++i)
      af[i] = *(const s16x8*)&As[(wr << 6) + (i << 4) + l15][quad << 3];
#pragma unroll
    for (int j = 0; j < 4; ++j)
      bfr[j] = *(const s16x8*)&Bs[(wc << 6) + (j << 4) + l15][quad << 3];
#pragma unroll
    for (int i = 0; i < 4; ++i)
#pragma unroll
      for (int j = 0; j < 4; ++j)
        acc[i][j] = MFMA16(af[i], bfr[j], acc[i][j]);
  }

#pragma unroll
  for (int jt = 0; jt < 4; ++jt) {
    int col = col0 + (wc << 6) + (jt << 4) + l15;
    float bv = ld1(Bp, col, bf);
#pragma unroll
    for (int i = 0; i < 4; ++i)
#pragma unroll
      for (int r = 0; r < 4; ++r) {
        int mrow = row0 + (wr << 6) + (i << 4) + (quad << 2) + r;
        float val = acc[i][jt][r] + bv;
        size_t off = (size_t)mrow * DIMC + col;
        if (bf) ((u16*)Out)[off] = f2bf(val);
        else    ((float*)Out)[off] = val;
      }
  }
}

// ---------------------------------------------------------------------------
extern "C" void kernel_launch(void* const* d_in, const int* in_sizes, int n_in,
                              void* d_out, int out_size, void* d_ws, size_t ws_size,
                              hipStream_t stream)
{
  const void* x    = d_in[0];   // (2,48,48,768)
  const void* rph  = d_in[1];   // (95,64)
  const void* rpw  = d_in[2];   // (95,64)
  const void* qkvw = d_in[3];   // (2304,768)
  const void* qkvb = d_in[4];   // (2304,)
  const void* pw   = d_in[5];   // (768,768)
  const void* pb   = d_in[6];   // (768,)

  // Workspace layout:
  //  [mode 16B] q,k bf16 (24,2304,64); vt bf16 (24,64,2304); aout bf16
  //  (2,2304,768)  -> base = 28,311,568 B
  //  bias tables fp16 (24,48,2304) x2   -> +10,616,832 B
  //  split-K partials f32 (S x O + S x l) if room.
  int* mode = (int*)d_ws;
  const size_t qkv_elems = (size_t)HEADS * NQ * HD;   // 3,538,944
  u16* q    = (u16*)((char*)d_ws + 16);
  u16* k    = q + qkv_elems;
  u16* vt   = k + qkv_elems;
  u16* aout = vt + qkv_elems;
  const size_t base = 16 + 4 * qkv_elems * 2;         // 28,311,568 B
  const size_t biasElems = (size_t)HEADS * 48 * NQ;   // 2,654,208 per table
  u16* bh_g = (u16*)((char*)d_ws + base);
  u16* bw_g = bh_g + biasElems;
  const size_t base2 = base + 2 * biasElems * 2;      // +10,616,832 B
  const size_t perO = (size_t)HEADS * NQ * HD * 4;    // 14,155,776 B
  const size_t perL = (size_t)HEADS * NQ * 4;         //    221,184 B

  int S = 1;
  if (ws_size >= base2 + 3 * (perO + perL)) S = 3;
  else if (ws_size >= base2 + 2 * (perO + perL)) S = 2;
  float* opart = (float*)((char*)d_ws + base2);
  float* lpart = (float*)((char*)d_ws + base2 + (size_t)S * perO);

  detect_k<<<1, 64, 0, stream>>>((const u16*)x, mode);
  qkv_gemm_k<<<dim3(18, 36), 256, 0, stream>>>(x, qkvw, qkvb, mode, q, k, vt);
  bias_gemm_k<<<dim3(432), 256, 0, stream>>>(q, rph, rpw, mode, bh_g, bw_g);
  attn_k<<<dim3(864 * S), 256, 0, stream>>>(q, k, vt, bh_g, bw_g,
                                            S, opart, lpart, aout);
  if (S > 1)
    combine_k<<<dim3(3456), 256, 0, stream>>>(opart, lpart, S, aout);
  proj_gemm_k<<<dim3(6, 36), 256, 0, stream>>>(aout, pw, pb, mode, d_out);
}

// Round 9
// 381.625 us; speedup vs baseline: 1.2730x; 1.2730x over previous
//
#include <hip/hip_runtime.h>
#include <hip/hip_bf16.h>
#include <stdint.h>

// Problem constants
#define NQ    2304          // H*W = 48*48 tokens
#define MROWS 4608          // B*NQ
#define DIMC  768
#define NHEAD 12
#define HEADS 24            // B*NH
#define HD    64

typedef unsigned int uint;
typedef unsigned short u16;
typedef __attribute__((ext_vector_type(8))) short s16x8;   // 8 bf16 = 4 VGPR
typedef __attribute__((ext_vector_type(4))) float f32x4;   // mfma acc

#define MFMA16(a, b, c) __builtin_amdgcn_mfma_f32_16x16x32_bf16((a), (b), (c), 0, 0, 0)

static __device__ __forceinline__ float bfbits2f(uint u) {
  union { uint i; float f; } c; c.i = u << 16; return c.f;
}
static __device__ __forceinline__ u16 f2bf(float f) {
  __hip_bfloat16 h = __float2bfloat16(f);
  union { __hip_bfloat16 h; u16 u; } c; c.h = h; return c.u;
}
static __device__ __forceinline__ u16 f2h(float f) {
  union { _Float16 h; u16 u; } c; c.h = (_Float16)f; return c.u;
}
static __device__ __forceinline__ float h2f(u16 u) {
  union { u16 u; _Float16 h; } c; c.u = u; return (float)c.h;
}
static __device__ __forceinline__ void dec8(uint4 p, float* f) {
  f[0] = bfbits2f(p.x & 0xFFFFu); f[1] = bfbits2f(p.x >> 16);
  f[2] = bfbits2f(p.y & 0xFFFFu); f[3] = bfbits2f(p.y >> 16);
  f[4] = bfbits2f(p.z & 0xFFFFu); f[5] = bfbits2f(p.z >> 16);
  f[6] = bfbits2f(p.w & 0xFFFFu); f[7] = bfbits2f(p.w >> 16);
}
// dual-dtype 8-element load -> fp32 (bf=1: bf16, bf=0: fp32)
static __device__ __forceinline__ void ld8(const void* p, size_t idx, int bf, float* f) {
  if (bf) { dec8(*(const uint4*)((const u16*)p + idx), f); }
  else {
    const float4* q = (const float4*)((const float*)p + idx);
    float4 a = q[0], b = q[1];
    f[0] = a.x; f[1] = a.y; f[2] = a.z; f[3] = a.w;
    f[4] = b.x; f[5] = b.y; f[6] = b.z; f[7] = b.w;
  }
}
static __device__ __forceinline__ float ld1(const void* p, size_t idx, int bf) {
  return bf ? bfbits2f(((const u16*)p)[idx]) : ((const float*)p)[idx];
}
// dual-dtype 8-element load -> packed bf16 (uint4)
static __device__ __forceinline__ uint4 ld8_to_bf(const void* p, size_t idx, int bf) {
  if (bf) return *(const uint4*)((const u16*)p + idx);
  float f[8]; ld8(p, idx, 0, f);
  uint4 u;
  u.x = (uint)f2bf(f[0]) | ((uint)f2bf(f[1]) << 16);
  u.y = (uint)f2bf(f[2]) | ((uint)f2bf(f[3]) << 16);
  u.z = (uint)f2bf(f[4]) | ((uint)f2bf(f[5]) << 16);
  u.w = (uint)f2bf(f[6]) | ((uint)f2bf(f[7]) << 16);
  return u;
}

// ---------------------------------------------------------------------------
// K0: dtype detector (unchanged — PASSED; do not touch).
// ---------------------------------------------------------------------------
__global__ __launch_bounds__(64) void detect_k(const u16* __restrict__ x,
                                               int* __restrict__ mode) {
  int t = threadIdx.x;
  int cnt = 0;
  for (int i = 0; i < 32; ++i) {
    uint u = x[(size_t)(t * 32 + i) * 2];
    uint e = (u >> 7) & 0xFFu;
    uint mag = u & 0x7FFFu;
    if (mag == 0 || (e >= 113 && e <= 133)) cnt++;
  }
#pragma unroll
  for (int d = 1; d < 64; d <<= 1) cnt += __shfl_xor(cnt, d);
  if (t == 0) mode[0] = (cnt > 1024) ? 1 : 0;
}

// ---------------------------------------------------------------------------
// K1: QKV projection, MFMA.  V stored TRANSPOSED: Vt[(bh*HD + d)*NQ + n]
// so attn loads V^T B-frags directly from global. Q/K row-major. (unchanged)
// ---------------------------------------------------------------------------
__global__ __launch_bounds__(256) void qkv_gemm_k(
    const void* __restrict__ Xp, const void* __restrict__ Wp,
    const void* __restrict__ Bq, const int* __restrict__ mode,
    u16* __restrict__ Q, u16* __restrict__ K, u16* __restrict__ Vt)
{
  __shared__ __align__(16) u16 As[128][40];
  __shared__ __align__(16) u16 Bs[128][40];
  const int bf = mode[0];
  const int t = threadIdx.x;
  const int w = t >> 6, l15 = t & 15, quad = (t >> 4) & 3;
  const int wr = w >> 1, wc = w & 1;
  const int row0 = blockIdx.y << 7, col0 = blockIdx.x << 7;
  const int lr = t >> 1, lk = (t & 1) << 4;

  f32x4 zero4 = {0.f, 0.f, 0.f, 0.f};
  f32x4 acc[4][4];
#pragma unroll
  for (int i = 0; i < 4; ++i)
#pragma unroll
    for (int j = 0; j < 4; ++j) acc[i][j] = zero4;

  for (int kt = 0; kt < DIMC; kt += 32) {
    __syncthreads();
    *(uint4*)&As[lr][lk]     = ld8_to_bf(Xp, (size_t)(row0 + lr) * DIMC + kt + lk, bf);
    *(uint4*)&As[lr][lk + 8] = ld8_to_bf(Xp, (size_t)(row0 + lr) * DIMC + kt + lk + 8, bf);
    *(uint4*)&Bs[lr][lk]     = ld8_to_bf(Wp, (size_t)(col0 + lr) * DIMC + kt + lk, bf);
    *(uint4*)&Bs[lr][lk + 8] = ld8_to_bf(Wp, (size_t)(col0 + lr) * DIMC + kt + lk + 8, bf);
    __syncthreads();
    s16x8 af[4], bfr[4];
#pragma unroll
    for (int i = 0; i < 4; ++i)
      af[i] = *(const s16x8*)&As[(wr << 6) + (i << 4) + l15][quad << 3];
#pragma unroll
    for (int j = 0; j < 4; ++j)
      bfr[j] = *(const s16x8*)&Bs[(wc << 6) + (j << 4) + l15][quad << 3];
#pragma unroll
    for (int i = 0; i < 4; ++i)
#pragma unroll
      for (int j = 0; j < 4; ++j)
        acc[i][j] = MFMA16(af[i], bfr[j], acc[i][j]);
  }

#pragma unroll
  for (int jt = 0; jt < 4; ++jt) {
    int col = col0 + (wc << 6) + (jt << 4) + l15;     // 0..2303
    int which = col / DIMC;
    int rem = col - which * DIMC;
    int head = rem >> 6, d = rem & 63;
    float bv = ld1(Bq, col, bf);
#pragma unroll
    for (int i = 0; i < 4; ++i)
#pragma unroll
      for (int r = 0; r < 4; ++r) {
        int mrow = row0 + (wr << 6) + (i << 4) + (quad << 2) + r;
        int b_ = (mrow >= NQ) ? 1 : 0;
        int n = mrow - b_ * NQ;
        u16 val = f2bf(acc[i][jt][r] + bv);
        size_t bh = (size_t)(b_ * NHEAD + head);
        if (which == 2)      Vt[(bh * HD + d) * NQ + n] = val;     // transposed
        else if (which == 1) K[(bh * NQ + n) * HD + d] = val;
        else                 Q[(bh * NQ + n) * HD + d] = val;
      }
  }
}

// ---------------------------------------------------------------------------
// K1b: bias precompute as MFMA GEMM (round 7, verified; unchanged).
// T[n][j] = q[n]·rel[j]; scatter to fp16 tables [bh][c][n].
// ---------------------------------------------------------------------------
__global__ __launch_bounds__(256) void bias_gemm_k(
    const u16* __restrict__ Qw,
    const void* __restrict__ rph, const void* __restrict__ rpw,
    const int* __restrict__ mode,
    u16* __restrict__ Bh_g, u16* __restrict__ Bw_g)
{
  __shared__ __align__(16) u16 As[128][72];
  __shared__ __align__(16) u16 Bs[192][72];
  const int bf = mode[0];
  const int t = threadIdx.x;
  const int w = t >> 6, l15 = t & 15, quad = (t >> 4) & 3;
  const int wr = w >> 1, wc = w & 1;
  const int blk = blockIdx.x;          // 0..431
  const int bhd = blk / 18;
  const int row0 = (blk - bhd * 18) << 7;

  // stage A: 128 q-rows x 64 k (bf16 native, coalesced)
  {
    int lr = t >> 1, lk = (t & 1) << 5;
    const u16* src = Qw + ((size_t)bhd * NQ + row0 + lr) * HD + lk;
    *(uint4*)&As[lr][lk]      = *(const uint4*)(src);
    *(uint4*)&As[lr][lk + 8]  = *(const uint4*)(src + 8);
    *(uint4*)&As[lr][lk + 16] = *(const uint4*)(src + 16);
    *(uint4*)&As[lr][lk + 24] = *(const uint4*)(src + 24);
  }
  // stage B: rows 0..94 = rel_h, 96..190 = rel_w (pad rows clamped)
  for (int e = t; e < 384; e += 256) {
    int row = e >> 1, k32 = (e & 1) << 5;
    int tab = (row >= 96) ? 1 : 0;
    int r2 = row - (tab ? 96 : 0);
    if (r2 > 94) r2 = 0;
    const void* src = tab ? rpw : rph;
    *(uint4*)&Bs[row][k32]      = ld8_to_bf(src, (size_t)r2 * HD + k32, bf);
    *(uint4*)&Bs[row][k32 + 8]  = ld8_to_bf(src, (size_t)r2 * HD + k32 + 8, bf);
    *(uint4*)&Bs[row][k32 + 16] = ld8_to_bf(src, (size_t)r2 * HD + k32 + 16, bf);
    *(uint4*)&Bs[row][k32 + 24] = ld8_to_bf(src, (size_t)r2 * HD + k32 + 24, bf);
  }
  __syncthreads();

  f32x4 zero4 = {0.f, 0.f, 0.f, 0.f};
  f32x4 acc[4][6];
#pragma unroll
  for (int i = 0; i < 4; ++i)
#pragma unroll
    for (int j = 0; j < 6; ++j) acc[i][j] = zero4;

#pragma unroll
  for (int ks = 0; ks < 2; ++ks) {
    s16x8 af[4], bfr[6];
#pragma unroll
    for (int i = 0; i < 4; ++i)
      af[i] = *(const s16x8*)&As[(wr << 6) + (i << 4) + l15][(ks << 5) + (quad << 3)];
#pragma unroll
    for (int j = 0; j < 6; ++j)
      bfr[j] = *(const s16x8*)&Bs[wc * 96 + (j << 4) + l15][(ks << 5) + (quad << 3)];
#pragma unroll
    for (int i = 0; i < 4; ++i)
#pragma unroll
      for (int j = 0; j < 6; ++j)
        acc[i][j] = MFMA16(af[i], bfr[j], acc[i][j]);
  }

  // scatter epilogue: col j of table tab -> c = coord(n)+47-j  (0..47 valid)
#pragma unroll
  for (int jt = 0; jt < 6; ++jt) {
    int col = wc * 96 + (jt << 4) + l15;     // 0..191
    int tab = (col >= 96) ? 1 : 0;
    int j = col - (tab ? 96 : 0);
    if (j >= 95) continue;
    u16* dstT = tab ? Bw_g : Bh_g;
#pragma unroll
    for (int i = 0; i < 4; ++i)
#pragma unroll
      for (int r = 0; r < 4; ++r) {
        int n = row0 + (wr << 6) + (i << 4) + (quad << 2) + r;
        int qh = (n * 10923) >> 19;
        int coord = tab ? (n - qh * 48) : qh;
        int c = coord + 47 - j;
        if (c >= 0 && c < 48)
          dstT[((size_t)bhd * 48 + c) * NQ + n] = f2h(acc[i][jt][r]);
      }
  }
}

// ---------------------------------------------------------------------------
// K2: MFMA flash attention, round 9: HALVE VMEM INSTRUCTION COUNT.
//  Evidence r0-r8: attn pinned at ~263 µs across occupancy 21/35/39%, with/
//  without prefetch, S=2/3 — time tracks TOTAL VMEM instruction count, not
//  waves. Model: each frag load touches 16 distinct cache lines (rows are
//  128B apart); TCP processes line sub-requests serially (~40 cy/instr);
//  486 wave-tiles/CU x 32 loads x ~40 cy ~= 620K cy = 264 µs. Fix: 2 q-
//  groups per wave (32 q-rows) sharing one set of K/V frag loads -> wave
//  count and VMEM instr count halve. Softmax/exchange/PV math identical to
//  r8, unrolled x2 with static indices. Block = 128 q-rows; grid 432*S.
// ---------------------------------------------------------------------------
__global__ __launch_bounds__(256) void attn_k(
    const u16* __restrict__ Qw, const u16* __restrict__ Kw,
    const u16* __restrict__ Vtg,
    const u16* __restrict__ Bh_g, const u16* __restrict__ Bw_g,
    int S, float* __restrict__ Opart, float* __restrict__ Lpart,
    u16* __restrict__ Aout)
{
  __shared__ __align__(16) u16 BhL[48][128];  // fp16 [kh][local qrow]  12.0 KB
  __shared__ __align__(16) u16 BwL[128][52];  // fp16 [local qrow][kw]  13.0 KB

  // XCD swizzle: nwg = 432*S (div by 8). XCD x runs heads 3x..3x+2 only ->
  // per-XCD K/V working set 1.76 MB -> L2-resident.
  const int bid = blockIdx.x;
  const int xcd = bid & 7;
  const int local = bid >> 3;            // [0, 54*S)
  const int per_head = 18 * S;
  const int head_l = local / per_head;   // 0..2
  const int rem = local - head_l * per_head;
  const int qb = rem / S;                // 0..17 (128-row q block)
  const int z = rem - qb * S;
  const int bhd = xcd * 3 + head_l;
  const int q0 = qb << 7;
  const int span = NQ / S;               // 2304/1152/768 (mult of 48 & 64)
  const int kt_lo = z * span, kt_hi = kt_lo + span;

  const int t = threadIdx.x;
  const int w = t >> 6, l15 = t & 15, quad = (t >> 4) & 3;
  const float scale = 0.125f;   // 64^-0.5

  const u16* kbase  = Kw  + (size_t)bhd * NQ * HD;
  const u16* vtbase = Vtg + (size_t)bhd * HD * NQ;
  const int q0w = q0 + (w << 5);         // wave's 32-row base (global token)

  // ---- LDS fill from precomputed fp16 tables (coalesced reads, raw copy)
  for (int e = t; e < 48 * 128; e += 256) {
    int c = e >> 7, r = e & 127;
    size_t gi = ((size_t)bhd * 48 + c) * NQ + q0 + r;
    BhL[c][r] = Bh_g[gi];
    BwL[r][c] = Bw_g[gi];
  }

  // Q B-frags, 2 groups of 16 q-rows: B[n=qrow=l15][k=quad*8+j]
  s16x8 qa0[2], qa1[2];
#pragma unroll
  for (int g = 0; g < 2; ++g) {
    const u16* qfrag = Qw + ((size_t)bhd * NQ + q0w + (g << 4) + l15) * HD + (quad << 3);
    qa0[g] = *(const s16x8*)(qfrag);
    qa1[g] = *(const s16x8*)(qfrag + 32);
  }

  __syncthreads();   // bias tables visible

  f32x4 zero4 = {0.f, 0.f, 0.f, 0.f};
  f32x4 acc_o[2][4];
#pragma unroll
  for (int g = 0; g < 2; ++g)
#pragma unroll
    for (int nc = 0; nc < 4; ++nc) acc_o[g][nc] = zero4;
  float l_st[2] = {0.f, 0.f};
  const int srcA = ((quad & 1) << 5) + l15;   // source quad 2*(quad&1)
  const int srcB = srcA + 16;
  const int hi = quad >> 1;
  int km = 0;         // kt0 % 48; kt_lo % 48 == 0 for all splits

  for (int kt0 = kt_lo; kt0 < kt_hi; kt0 += 64) {
    // S^T = K Q^T for BOTH q-groups, sharing K-frag loads (halved VMEM).
    f32x4 acc_s[2][4];
#pragma unroll
    for (int nc = 0; nc < 4; ++nc) {
      const u16* kp = kbase + (size_t)(kt0 + (nc << 4) + l15) * HD + (quad << 3);
      s16x8 kb0 = *(const s16x8*)(kp);
      s16x8 kb1 = *(const s16x8*)(kp + 32);
      f32x4 a0 = MFMA16(kb0, qa0[0], zero4);
      acc_s[0][nc] = MFMA16(kb1, qa1[0], a0);
      f32x4 a1 = MFMA16(kb0, qa0[1], zero4);
      acc_s[1][nc] = MFMA16(kb1, qa1[1], a1);
    }

    // softmax per group -> packed bf16 W words (keys for this lane's qrow)
    int kh0 = (kt0 * 10923) >> 19;
    int thr = (kh0 + 1) * 48 - kt0;          // local key >= thr -> kh0+1
    uint Wq[2][8];
#pragma unroll
    for (int g = 0; g < 2; ++g) {
      int qrl = (w << 5) + (g << 4) + l15;   // local q row for this group
      float bh0v = h2f(BhL[kh0][qrl]);
      float bh1v = h2f(BhL[kh0 + 1][qrl]);   // kh0 <= 46 always
      float sum = 0.f;
#pragma unroll
      for (int nc = 0; nc < 4; ++nc) {
        int bnc = km + (nc << 4);
        bnc = (bnc >= 48) ? bnc - 48 : bnc;  // in {0,16,32}; +4*quad+3 <= 47
        uint2 pv = *(const uint2*)&BwL[qrl][bnc + (quad << 2)];
        float b0 = h2f((u16)(pv.x & 0xFFFFu));
        float b1 = h2f((u16)(pv.x >> 16));
        float b2 = h2f((u16)(pv.y & 0xFFFFu));
        float b3 = h2f((u16)(pv.y >> 16));
        int kl = (nc << 4) + (quad << 2);
        float e0 = __expf(acc_s[g][nc][0] * scale + ((kl     >= thr) ? bh1v : bh0v) + b0);
        float e1 = __expf(acc_s[g][nc][1] * scale + ((kl + 1 >= thr) ? bh1v : bh0v) + b1);
        float e2 = __expf(acc_s[g][nc][2] * scale + ((kl + 2 >= thr) ? bh1v : bh0v) + b2);
        float e3 = __expf(acc_s[g][nc][3] * scale + ((kl + 3 >= thr) ? bh1v : bh0v) + b3);
        sum += (e0 + e1) + (e2 + e3);
        Wq[g][2 * nc]     = (uint)f2bf(e0) | ((uint)f2bf(e1) << 16);
        Wq[g][2 * nc + 1] = (uint)f2bf(e2) | ((uint)f2bf(e3) << 16);
      }
      l_st[g] += sum;
    }

    // P V for both groups, sharing V-frag loads (halved VMEM).
    // half h covers keys kt0+32h .. kt0+32h+31; W words [4h..4h+3].
#pragma unroll
    for (int h = 0; h < 2; ++h) {
      s16x8 vb[4];
#pragma unroll
      for (int nc = 0; nc < 4; ++nc)
        vb[nc] = *(const s16x8*)(vtbase + (size_t)((nc << 4) + l15) * NQ
                                 + kt0 + (h << 5) + (quad << 3));
#pragma unroll
      for (int g = 0; g < 2; ++g) {
        uint e0 = __shfl(Wq[g][4*h+0], srcA), e1 = __shfl(Wq[g][4*h+1], srcA);
        uint e2 = __shfl(Wq[g][4*h+2], srcA), e3 = __shfl(Wq[g][4*h+3], srcA);
        uint g0 = __shfl(Wq[g][4*h+0], srcB), g1 = __shfl(Wq[g][4*h+1], srcB);
        uint g2 = __shfl(Wq[g][4*h+2], srcB), g3 = __shfl(Wq[g][4*h+3], srcB);
        union { uint u[4]; s16x8 v; } pf;
        pf.u[0] = hi ? e2 : e0; pf.u[1] = hi ? e3 : e1;
        pf.u[2] = hi ? g2 : g0; pf.u[3] = hi ? g3 : g1;
#pragma unroll
        for (int nc = 0; nc < 4; ++nc)
          acc_o[g][nc] = MFMA16(pf.v, vb[nc], acc_o[g][nc]);
      }
    }
    km += 16;
    if (km >= 48) km -= 48;
  }

  // epilogue per group
#pragma unroll
  for (int g = 0; g < 2; ++g) {
    float lg = l_st[g];
    lg += __shfl_xor(lg, 16);
    lg += __shfl_xor(lg, 32);
    if (S > 1) {
      float* Op = Opart + ((size_t)(z * HEADS + bhd) * NQ + q0) * HD;
#pragma unroll
      for (int r = 0; r < 4; ++r) {
        int row = (w << 5) + (g << 4) + (quad << 2) + r;
#pragma unroll
        for (int nc = 0; nc < 4; ++nc)
          Op[(size_t)row * HD + (nc << 4) + l15] = acc_o[g][nc][r];
      }
      if (quad == 0)
        Lpart[(size_t)(z * HEADS + bhd) * NQ + q0w + (g << 4) + l15] = lg;
    } else {
      int b_ = bhd / NHEAD, head = bhd - b_ * NHEAD;
      float invl = 1.f / lg;
      int bsrc = (quad << 4) + (quad << 2);
#pragma unroll
      for (int r = 0; r < 4; ++r) {
        float inv = __shfl(invl, bsrc + r);   // lane with l15 == 4*quad+r
        int token = q0 + (w << 5) + (g << 4) + (quad << 2) + r;
        u16* dst = Aout + ((size_t)b_ * NQ + token) * DIMC + (head << 6);
#pragma unroll
        for (int nc = 0; nc < 4; ++nc)
          dst[(nc << 4) + l15] = f2bf(acc_o[g][nc][r] * inv);
      }
    }
  }
}

// ---------------------------------------------------------------------------
// K2b: combine split-K partials: O = (sum_z O_z) / (sum_z l_z), store bf16.
// ---------------------------------------------------------------------------
__global__ __launch_bounds__(256) void combine_k(
    const float* __restrict__ Op, const float* __restrict__ Lp,
    int S, u16* __restrict__ Aout)
{
  int idx = blockIdx.x * 256 + threadIdx.x;   // 0 .. 884735
  int m = idx / 192;                          // row 0..4607 (DIMC/4 = 192)
  int cq = idx - m * 192;
  int ccol = cq << 2;
  int head = ccol >> 6, d0 = ccol & 63;
  int b_ = (m >= NQ) ? 1 : 0;
  int n = m - b_ * NQ;
  int bh = b_ * NHEAD + head;
  float ox = 0.f, oy = 0.f, oz = 0.f, ow = 0.f, ls = 0.f;
  for (int zz = 0; zz < S; ++zz) {
    const float* ob = Op + ((size_t)(zz * HEADS + bh) * NQ + n) * HD + d0;
    float4 v = *(const float4*)ob;
    ox += v.x; oy += v.y; oz += v.z; ow += v.w;
    ls += Lp[(size_t)(zz * HEADS + bh) * NQ + n];
  }
  float inv = 1.f / ls;
  u16* dst = Aout + (size_t)m * DIMC + ccol;
  dst[0] = f2bf(ox * inv); dst[1] = f2bf(oy * inv);
  dst[2] = f2bf(oz * inv); dst[3] = f2bf(ow * inv);
}

// ---------------------------------------------------------------------------
// K3: output projection, MFMA (unchanged).
// ---------------------------------------------------------------------------
__global__ __launch_bounds__(256) void proj_gemm_k(
    const u16* __restrict__ A, const void* __restrict__ Wp,
    const void* __restrict__ Bp, const int* __restrict__ mode,
    void* __restrict__ Out)
{
  __shared__ __align__(16) u16 As[128][40];
  __shared__ __align__(16) u16 Bs[128][40];
  const int bf = mode[0];
  const int t = threadIdx.x;
  const int w = t >> 6, l15 = t & 15, quad = (t >> 4) & 3;
  const int wr = w >> 1, wc = w & 1;
  const int row0 = blockIdx.y << 7, col0 = blockIdx.x << 7;
  const int lr = t >> 1, lk = (t & 1) << 4;

  f32x4 zero4 = {0.f, 0.f, 0.f, 0.f};
  f32x4 acc[4][4];
#pragma unroll
  for (int i = 0; i < 4; ++i)
#pragma unroll
    for (int j = 0; j < 4; ++j) acc[i][j] = zero4;

  for (int kt = 0; kt < DIMC; kt += 32) {
    __syncthreads();
    *(uint4*)&As[lr][lk]     = *(const uint4*)(A + (size_t)(row0 + lr) * DIMC + kt + lk);
    *(uint4*)&As[lr][lk + 8] = *(const uint4*)(A + (size_t)(row0 + lr) * DIMC + kt + lk + 8);
    *(uint4*)&Bs[lr][lk]     = ld8_to_bf(Wp, (size_t)(col0 + lr) * DIMC + kt + lk, bf);
    *(uint4*)&Bs[lr][lk + 8] = ld8_to_bf(Wp, (size_t)(col0 + lr) * DIMC + kt + lk + 8, bf);
    __syncthreads();
    s16x8 af[4], bfr[4];
#pragma unroll
    for (int i = 0; i < 4; ++i)
      af[i] = *(const s16x8*)&As[(wr << 6) + (i << 4) + l15][quad << 3];
#pragma unroll
    for (int j = 0; j < 4; ++j)
      bfr[j] = *(const s16x8*)&Bs[(wc << 6) + (j << 4) + l15][quad << 3];
#pragma unroll
    for (int i = 0; i < 4; ++i)
#pragma unroll
      for (int j = 0; j < 4; ++j)
        acc[i][j] = MFMA16(af[i], bfr[j], acc[i][j]);
  }

#pragma unroll
  for (int jt = 0; jt < 4; ++jt) {
    int col = col0 + (wc << 6) + (jt << 4) + l15;
    float bv = ld1(Bp, col, bf);
#pragma unroll
    for (int i = 0; i < 4; ++i)
#pragma unroll
      for (int r = 0; r < 4; ++r) {
        int mrow = row0 + (wr << 6) + (i << 4) + (quad << 2) + r;
        float val = acc[i][jt][r] + bv;
        size_t off = (size_t)mrow * DIMC + col;
        if (bf) ((u16*)Out)[off] = f2bf(val);
        else    ((float*)Out)[off] = val;
      }
  }
}

// ---------------------------------------------------------------------------
extern "C" void kernel_launch(void* const* d_in, const int* in_sizes, int n_in,
                              void* d_out, int out_size, void* d_ws, size_t ws_size,
                              hipStream_t stream)
{
  const void* x    = d_in[0];   // (2,48,48,768)
  const void* rph  = d_in[1];   // (95,64)
  const void* rpw  = d_in[2];   // (95,64)
  const void* qkvw = d_in[3];   // (2304,768)
  const void* qkvb = d_in[4];   // (2304,)
  const void* pw   = d_in[5];   // (768,768)
  const void* pb   = d_in[6];   // (768,)

  // Workspace layout:
  //  [mode 16B] q,k bf16 (24,2304,64); vt bf16 (24,64,2304); aout bf16
  //  (2,2304,768)  -> base = 28,311,568 B
  //  bias tables fp16 (24,48,2304) x2   -> +10,616,832 B
  //  split-K partials f32 (S x O + S x l) if room.
  int* mode = (int*)d_ws;
  const size_t qkv_elems = (size_t)HEADS * NQ * HD;   // 3,538,944
  u16* q    = (u16*)((char*)d_ws + 16);
  u16* k    = q + qkv_elems;
  u16* vt   = k + qkv_elems;
  u16* aout = vt + qkv_elems;
  const size_t base = 16 + 4 * qkv_elems * 2;         // 28,311,568 B
  const size_t biasElems = (size_t)HEADS * 48 * NQ;   // 2,654,208 per table
  u16* bh_g = (u16*)((char*)d_ws + base);
  u16* bw_g = bh_g + biasElems;
  const size_t base2 = base + 2 * biasElems * 2;      // +10,616,832 B
  const size_t perO = (size_t)HEADS * NQ * HD * 4;    // 14,155,776 B
  const size_t perL = (size_t)HEADS * NQ * 4;         //    221,184 B

  int S = 1;
  if (ws_size >= base2 + 3 * (perO + perL)) S = 3;
  else if (ws_size >= base2 + 2 * (perO + perL)) S = 2;
  float* opart = (float*)((char*)d_ws + base2);
  float* lpart = (float*)((char*)d_ws + base2 + (size_t)S * perO);

  detect_k<<<1, 64, 0, stream>>>((const u16*)x, mode);
  qkv_gemm_k<<<dim3(18, 36), 256, 0, stream>>>(x, qkvw, qkvb, mode, q, k, vt);
  bias_gemm_k<<<dim3(432), 256, 0, stream>>>(q, rph, rpw, mode, bh_g, bw_g);
  attn_k<<<dim3(432 * S), 256, 0, stream>>>(q, k, vt, bh_g, bw_g,
                                            S, opart, lpart, aout);
  if (S > 1)
    combine_k<<<dim3(3456), 256, 0, stream>>>(opart, lpart, S, aout);
  proj_gemm_k<<<dim3(6, 36), 256, 0, stream>>>(aout, pw, pb, mode, d_out);
}